// Round 7
// baseline (507.945 us; speedup 1.0000x reference)
//
#include <hip/hip_runtime.h>
#include <hip/hip_cooperative_groups.h>

// 22-qubit QAOA state-vector sim — SINGLE cooperative kernel, 3 phases.
//   P1: init + phase1 + layer1 bits 0-13  (contiguous 16384-elem tile/block)
//   P2: layer1 bits 14-21 + phase2 + layer2 bits 14-21 (64-col combs, 256B segs)
//   P3: layer2 bits 0-13 + fused |c|^2*hS reduce
// Grid 256 x 1024 (1 block/CU), grid.sync() between phases.
// Butterfly c = cb*c + i*sb*partner is symmetric -> run stages where the
// partner lives: register bits (FMA), lane bits (packed shfl), wave bits
// (LDS transpose). State fp16-packed in HBM/LDS, all math f32.

#define NB    256
#define TPB   1024
#define R     16

namespace cg = cooperative_groups;

typedef __fp16 h2_t __attribute__((ext_vector_type(2)));
union PkU { unsigned u; h2_t h; };

__device__ __forceinline__ unsigned pk(float x, float y) {
    PkU p; p.h = __builtin_amdgcn_cvt_pkrtz(x, y); return p.u;
}
__device__ __forceinline__ float2 unpk(unsigned v) {
    PkU p; p.u = v; return make_float2((float)p.h.x, (float)p.h.y);
}

// register butterfly on register-index bit MASK (f32)
#define REGSTAGE(MASK, CB, SB) {                                  \
    _Pragma("unroll")                                             \
    for (int r0 = 0; r0 < R; ++r0) {                              \
        if ((r0 & (MASK)) == 0) {                                 \
            const int r1 = r0 | (MASK);                           \
            float t0r = re[r0], t0i = im[r0];                     \
            float t1r = re[r1], t1i = im[r1];                     \
            re[r0] = (CB) * t0r - (SB) * t1i;                     \
            im[r0] = (CB) * t0i + (SB) * t1r;                     \
            re[r1] = (CB) * t1r - (SB) * t0i;                     \
            im[r1] = (CB) * t1i + (SB) * t0r;                     \
        } } }

// cross-lane butterfly, one packed-half2 shuffle per element (partner term is
// scaled by sb ~ 0.01 -> fp16 partner rounding negligible)
#define SHFLSTAGE(MASK, CB, SB) {                                 \
    _Pragma("unroll")                                             \
    for (int r = 0; r < R; ++r) {                                 \
        unsigned pv = (unsigned)__shfl_xor((int)pk(re[r], im[r]), (MASK), 64); \
        float2 p = unpk(pv);                                      \
        float tr = re[r], ti = im[r];                             \
        re[r] = (CB) * tr - (SB) * p.y;                           \
        im[r] = (CB) * ti + (SB) * p.x;                           \
    } }

__global__ __launch_bounds__(TPB, 4) void k_fused(
    const float* __restrict__ h, const float* __restrict__ hS,
    const float* __restrict__ gam, const float* __restrict__ bet,
    unsigned* __restrict__ st, float* __restrict__ partial,
    float* __restrict__ out)
{
    __shared__ unsigned sC[16384];   // 64 KB packed half2
    cg::grid_group grid = cg::this_grid();
    const unsigned t = threadIdx.x, lane = t & 63u, w = t >> 6;   // w: 0..15
    const unsigned b = blockIdx.x;
    const float cb1 = __cosf(bet[0]), sb1 = __sinf(bet[0]);
    const float cb2 = __cosf(bet[1]), sb2 = __sinf(bet[1]);
    const float g1 = gam[0], g2 = gam[1];
    float re[R], im[R];

    // ================= P1: init + phase1 + layer1 bits 0-13 =================
    // tile = 16384 contiguous elems at base = b<<14.
    // map A: i = lane | w<<6 | r<<10 ; map B: i = lane | r<<6 | w<<10
    {
        const size_t base = (size_t)b << 14;
        #pragma unroll
        for (int r = 0; r < R; ++r) {
            unsigned i = lane | (w << 6) | ((unsigned)r << 10);
            float s, c;
            __sincosf(g1 * h[base + i], &s, &c);
            re[r] = c * 0x1p-11f;   // 1/sqrt(2^22)
            im[r] = s * 0x1p-11f;
        }
        REGSTAGE(1, cb1, sb1)  REGSTAGE(2, cb1, sb1)
        REGSTAGE(4, cb1, sb1)  REGSTAGE(8, cb1, sb1)       // bits 10-13
        SHFLSTAGE(1,  cb1, sb1) SHFLSTAGE(2,  cb1, sb1)    // bits 0,1
        SHFLSTAGE(4,  cb1, sb1) SHFLSTAGE(8,  cb1, sb1)    // bits 2,3
        SHFLSTAGE(16, cb1, sb1) SHFLSTAGE(32, cb1, sb1)    // bits 4,5
        #pragma unroll
        for (int r = 0; r < R; ++r)
            sC[lane | (w << 6) | ((unsigned)r << 10)] = pk(re[r], im[r]);
        __syncthreads();
        #pragma unroll
        for (int r = 0; r < R; ++r) {
            float2 v = unpk(sC[lane | ((unsigned)r << 6) | (w << 10)]);
            re[r] = v.x; im[r] = v.y;
        }
        REGSTAGE(1, cb1, sb1)  REGSTAGE(2, cb1, sb1)
        REGSTAGE(4, cb1, sb1)  REGSTAGE(8, cb1, sb1)       // bits 6-9
        #pragma unroll
        for (int r = 0; r < R; ++r)
            st[base + (lane | ((unsigned)r << 6) | (w << 10))] = pk(re[r], im[r]);
    }
    __threadfence();
    grid.sync();

    // ======= P2: layer1 bits 14-21 + phase2 + layer2 bits 14-21 =======
    // lo columns g0 = b*64 .. +63 (lane), hi = bits 14-21 (256 values).
    // map A: hi = w | r<<4 ; map B: hi = r | w<<4. Global idx = hi<<14 | g0 | lane.
    {
        const unsigned g0 = b << 6;
        #pragma unroll
        for (int r = 0; r < R; ++r) {
            size_t gi = ((size_t)(w | ((unsigned)r << 4)) << 14) | g0 | lane;
            float2 v = unpk(st[gi]);
            re[r] = v.x; im[r] = v.y;
        }
        REGSTAGE(1, cb1, sb1)  REGSTAGE(2, cb1, sb1)
        REGSTAGE(4, cb1, sb1)  REGSTAGE(8, cb1, sb1)       // bits 18-21
        // T: A -> B  (LDS idx = lane | hi<<6)
        #pragma unroll
        for (int r = 0; r < R; ++r)
            sC[lane | ((w | ((unsigned)r << 4)) << 6)] = pk(re[r], im[r]);
        __syncthreads();
        #pragma unroll
        for (int r = 0; r < R; ++r) {
            float2 v = unpk(sC[lane | (((unsigned)r | (w << 4)) << 6)]);
            re[r] = v.x; im[r] = v.y;
        }
        REGSTAGE(1, cb1, sb1)  REGSTAGE(2, cb1, sb1)
        REGSTAGE(4, cb1, sb1)  REGSTAGE(8, cb1, sb1)       // bits 14-17; L1 done
        // phase2
        #pragma unroll
        for (int r = 0; r < R; ++r) {
            size_t gi = ((size_t)((unsigned)r | (w << 4)) << 14) | g0 | lane;
            float s, c;
            __sincosf(g2 * h[gi], &s, &c);
            float tr = re[r], ti = im[r];
            re[r] = tr * c - ti * s;
            im[r] = tr * s + ti * c;
        }
        // layer2 high
        REGSTAGE(1, cb2, sb2)  REGSTAGE(2, cb2, sb2)
        REGSTAGE(4, cb2, sb2)  REGSTAGE(8, cb2, sb2)       // bits 14-17
        __syncthreads();   // WAR on sC
        #pragma unroll
        for (int r = 0; r < R; ++r)
            sC[lane | (((unsigned)r | (w << 4)) << 6)] = pk(re[r], im[r]);
        __syncthreads();
        #pragma unroll
        for (int r = 0; r < R; ++r) {
            float2 v = unpk(sC[lane | ((w | ((unsigned)r << 4)) << 6)]);
            re[r] = v.x; im[r] = v.y;
        }
        REGSTAGE(1, cb2, sb2)  REGSTAGE(2, cb2, sb2)
        REGSTAGE(4, cb2, sb2)  REGSTAGE(8, cb2, sb2)       // bits 18-21
        #pragma unroll
        for (int r = 0; r < R; ++r) {
            size_t gi = ((size_t)(w | ((unsigned)r << 4)) << 14) | g0 | lane;
            st[gi] = pk(re[r], im[r]);
        }
    }
    __threadfence();
    grid.sync();

    // ============ P3: layer2 bits 0-13 + fused |c|^2 * hS reduce ============
    {
        const size_t base = (size_t)b << 14;
        #pragma unroll
        for (int r = 0; r < R; ++r) {
            float2 v = unpk(st[base + (lane | (w << 6) | ((unsigned)r << 10))]);
            re[r] = v.x; im[r] = v.y;
        }
        REGSTAGE(1, cb2, sb2)  REGSTAGE(2, cb2, sb2)
        REGSTAGE(4, cb2, sb2)  REGSTAGE(8, cb2, sb2)       // bits 10-13
        SHFLSTAGE(1,  cb2, sb2) SHFLSTAGE(2,  cb2, sb2)
        SHFLSTAGE(4,  cb2, sb2) SHFLSTAGE(8,  cb2, sb2)
        SHFLSTAGE(16, cb2, sb2) SHFLSTAGE(32, cb2, sb2)    // bits 0-5
        __syncthreads();   // WAR on sC from P2
        #pragma unroll
        for (int r = 0; r < R; ++r)
            sC[lane | (w << 6) | ((unsigned)r << 10)] = pk(re[r], im[r]);
        __syncthreads();
        #pragma unroll
        for (int r = 0; r < R; ++r) {
            float2 v = unpk(sC[lane | ((unsigned)r << 6) | (w << 10)]);
            re[r] = v.x; im[r] = v.y;
        }
        REGSTAGE(1, cb2, sb2)  REGSTAGE(2, cb2, sb2)
        REGSTAGE(4, cb2, sb2)  REGSTAGE(8, cb2, sb2)       // bits 6-9
        float acc = 0.f;
        #pragma unroll
        for (int r = 0; r < R; ++r) {
            unsigned i = lane | ((unsigned)r << 6) | (w << 10);
            acc = fmaf(re[r] * re[r] + im[r] * im[r], hS[base + i], acc);
        }
        #pragma unroll
        for (int off = 32; off >= 1; off >>= 1)
            acc += __shfl_down(acc, off, 64);
        float* sF = (float*)sC;
        __syncthreads();   // WAR on sC
        if (lane == 0) sF[w] = acc;
        __syncthreads();
        if (t == 0) {
            float s = 0.f;
            #pragma unroll
            for (int i = 0; i < TPB / 64; ++i) s += sF[i];
            partial[b] = s;
        }
    }
    __threadfence();
    grid.sync();

    // ---------------- final reduce: block 0 sums 256 partials ----------------
    if (b == 0) {
        float v = (t < NB) ? partial[t] : 0.f;
        #pragma unroll
        for (int off = 32; off >= 1; off >>= 1)
            v += __shfl_down(v, off, 64);
        float* sF = (float*)sC;
        __syncthreads();
        if (lane == 0) sF[w] = v;
        __syncthreads();
        if (t == 0) {
            float s = 0.f;
            #pragma unroll
            for (int i = 0; i < (NB + 63) / 64; ++i) s += sF[i];
            out[0] = s;
        }
    }
}

extern "C" void kernel_launch(void* const* d_in, const int* in_sizes, int n_in,
                              void* d_out, int out_size, void* d_ws, size_t ws_size,
                              hipStream_t stream)
{
    (void)in_sizes; (void)n_in; (void)out_size; (void)ws_size;
    const float* h   = (const float*)d_in[0];
    const float* hS  = (const float*)d_in[1];
    const float* gam = (const float*)d_in[2];
    const float* bet = (const float*)d_in[3];
    float*    partial = (float*)d_ws;                       // 256 floats
    unsigned* st      = (unsigned*)((char*)d_ws + 4096);    // 16 MB half2 state
    float*    out     = (float*)d_out;

    void* args[] = { (void*)&h, (void*)&hS, (void*)&gam, (void*)&bet,
                     (void*)&st, (void*)&partial, (void*)&out };
    hipLaunchCooperativeKernel((void*)k_fused, dim3(NB), dim3(TPB),
                               args, 0, stream);
}

// Round 8
// 322.193 us; speedup vs baseline: 1.5765x; 1.5765x over previous
//
#include <hip/hip_runtime.h>

// 22-qubit QAOA state-vector sim — single cooperative-launch kernel, 3 phases,
// HAND-ROLLED grid barriers (R7 showed cg::grid.sync() costs ~100+ us each:
// k_fused 420 us with VALUBusy 6.5%, HBM 3.5%, conflicts 0 -> all idle).
//   P1: init + phase1 + layer1 bits 0-13  (contiguous 16384-elem tile/block)
//   P2: layer1 bits 14-21 + phase2 + layer2 bits 14-21 (64-col combs, 256B segs)
//   P3: layer2 bits 0-13 + fused |c|^2*hS reduce; LAST block sums partials.
// Barrier: thread0 fetch_add(ACQ_REL,AGENT) + ACQUIRE spin w/ s_sleep; a tiny
// init kernel zeroes counters each call (d_ws re-poisoned 0xAA by harness).
// __syncthreads pre-arrival drains wave stores to L2; release half emits L2
// writeback; __threadfence post-barrier invalidates stale clean lines (P1
// leaves own-tile lines clean in this XCD's L2; P2 remote writes overwrite).

#define NB    256
#define TPB   1024
#define R     16

typedef __fp16 h2_t __attribute__((ext_vector_type(2)));
union PkU { unsigned u; h2_t h; };

__device__ __forceinline__ unsigned pk(float x, float y) {
    PkU p; p.h = __builtin_amdgcn_cvt_pkrtz(x, y); return p.u;
}
__device__ __forceinline__ float2 unpk(unsigned v) {
    PkU p; p.u = v; return make_float2((float)p.h.x, (float)p.h.y);
}

__device__ __forceinline__ void gbar(unsigned* cnt) {
    __syncthreads();                       // drains all waves' stores (vmcnt 0)
    if (threadIdx.x == 0) {
        __hip_atomic_fetch_add(cnt, 1u, __ATOMIC_ACQ_REL, __HIP_MEMORY_SCOPE_AGENT);
        while (__hip_atomic_load(cnt, __ATOMIC_ACQUIRE, __HIP_MEMORY_SCOPE_AGENT) < NB)
            __builtin_amdgcn_s_sleep(2);
    }
    __syncthreads();
    __threadfence();                       // invalidate stale clean L2 lines
}

// register butterfly on register-index bit MASK (f32)
#define REGSTAGE(MASK, CB, SB) {                                  \
    _Pragma("unroll")                                             \
    for (int r0 = 0; r0 < R; ++r0) {                              \
        if ((r0 & (MASK)) == 0) {                                 \
            const int r1 = r0 | (MASK);                           \
            float t0r = re[r0], t0i = im[r0];                     \
            float t1r = re[r1], t1i = im[r1];                     \
            re[r0] = (CB) * t0r - (SB) * t1i;                     \
            im[r0] = (CB) * t0i + (SB) * t1r;                     \
            re[r1] = (CB) * t1r - (SB) * t0i;                     \
            im[r1] = (CB) * t1i + (SB) * t0r;                     \
        } } }

// cross-lane butterfly, one packed-half2 shuffle per element
#define SHFLSTAGE(MASK, CB, SB) {                                 \
    _Pragma("unroll")                                             \
    for (int r = 0; r < R; ++r) {                                 \
        unsigned pv = (unsigned)__shfl_xor((int)pk(re[r], im[r]), (MASK), 64); \
        float2 p = unpk(pv);                                      \
        float tr = re[r], ti = im[r];                             \
        re[r] = (CB) * tr - (SB) * p.y;                           \
        im[r] = (CB) * ti + (SB) * p.x;                           \
    } }

__global__ void k_init(unsigned* bar) {
    if (threadIdx.x < 3) bar[threadIdx.x * 32] = 0u;   // bar0, bar1, done
}

__global__ __launch_bounds__(TPB, 4) void k_fused(
    const float* __restrict__ h, const float* __restrict__ hS,
    const float* __restrict__ gam, const float* __restrict__ bet,
    unsigned* __restrict__ bar, unsigned* __restrict__ st,
    float* __restrict__ partial, float* __restrict__ out)
{
    __shared__ unsigned sC[16384];   // 64 KB packed half2
    const unsigned t = threadIdx.x, lane = t & 63u, w = t >> 6;   // w: 0..15
    const unsigned b = blockIdx.x;
    const float cb1 = __cosf(bet[0]), sb1 = __sinf(bet[0]);
    const float cb2 = __cosf(bet[1]), sb2 = __sinf(bet[1]);
    const float g1 = gam[0], g2 = gam[1];
    float re[R], im[R];

    // ================= P1: init + phase1 + layer1 bits 0-13 =================
    // tile = 16384 contiguous elems at base = b<<14.
    // map A: i = lane | w<<6 | r<<10 ; map B: i = lane | r<<6 | w<<10
    {
        const size_t base = (size_t)b << 14;
        #pragma unroll
        for (int r = 0; r < R; ++r) {
            unsigned i = lane | (w << 6) | ((unsigned)r << 10);
            float s, c;
            __sincosf(g1 * h[base + i], &s, &c);
            re[r] = c * 0x1p-11f;   // 1/sqrt(2^22)
            im[r] = s * 0x1p-11f;
        }
        REGSTAGE(1, cb1, sb1)  REGSTAGE(2, cb1, sb1)
        REGSTAGE(4, cb1, sb1)  REGSTAGE(8, cb1, sb1)       // bits 10-13
        SHFLSTAGE(1,  cb1, sb1) SHFLSTAGE(2,  cb1, sb1)    // bits 0,1
        SHFLSTAGE(4,  cb1, sb1) SHFLSTAGE(8,  cb1, sb1)    // bits 2,3
        SHFLSTAGE(16, cb1, sb1) SHFLSTAGE(32, cb1, sb1)    // bits 4,5
        #pragma unroll
        for (int r = 0; r < R; ++r)
            sC[lane | (w << 6) | ((unsigned)r << 10)] = pk(re[r], im[r]);
        __syncthreads();
        #pragma unroll
        for (int r = 0; r < R; ++r) {
            float2 v = unpk(sC[lane | ((unsigned)r << 6) | (w << 10)]);
            re[r] = v.x; im[r] = v.y;
        }
        REGSTAGE(1, cb1, sb1)  REGSTAGE(2, cb1, sb1)
        REGSTAGE(4, cb1, sb1)  REGSTAGE(8, cb1, sb1)       // bits 6-9
        #pragma unroll
        for (int r = 0; r < R; ++r)
            st[base + (lane | ((unsigned)r << 6) | (w << 10))] = pk(re[r], im[r]);
    }
    gbar(&bar[0]);

    // ======= P2: layer1 bits 14-21 + phase2 + layer2 bits 14-21 =======
    // lo columns g0 = b*64 .. +63 (lane), hi = bits 14-21 (256 values).
    // map A: hi = w | r<<4 ; map B: hi = r | w<<4. Global idx = hi<<14 | g0 | lane.
    {
        const unsigned g0 = b << 6;
        #pragma unroll
        for (int r = 0; r < R; ++r) {
            size_t gi = ((size_t)(w | ((unsigned)r << 4)) << 14) | g0 | lane;
            float2 v = unpk(st[gi]);
            re[r] = v.x; im[r] = v.y;
        }
        REGSTAGE(1, cb1, sb1)  REGSTAGE(2, cb1, sb1)
        REGSTAGE(4, cb1, sb1)  REGSTAGE(8, cb1, sb1)       // bits 18-21
        // T: A -> B  (LDS idx = lane | hi<<6)
        #pragma unroll
        for (int r = 0; r < R; ++r)
            sC[lane | ((w | ((unsigned)r << 4)) << 6)] = pk(re[r], im[r]);
        __syncthreads();
        #pragma unroll
        for (int r = 0; r < R; ++r) {
            float2 v = unpk(sC[lane | (((unsigned)r | (w << 4)) << 6)]);
            re[r] = v.x; im[r] = v.y;
        }
        REGSTAGE(1, cb1, sb1)  REGSTAGE(2, cb1, sb1)
        REGSTAGE(4, cb1, sb1)  REGSTAGE(8, cb1, sb1)       // bits 14-17; L1 done
        // phase2
        #pragma unroll
        for (int r = 0; r < R; ++r) {
            size_t gi = ((size_t)((unsigned)r | (w << 4)) << 14) | g0 | lane;
            float s, c;
            __sincosf(g2 * h[gi], &s, &c);
            float tr = re[r], ti = im[r];
            re[r] = tr * c - ti * s;
            im[r] = tr * s + ti * c;
        }
        // layer2 high
        REGSTAGE(1, cb2, sb2)  REGSTAGE(2, cb2, sb2)
        REGSTAGE(4, cb2, sb2)  REGSTAGE(8, cb2, sb2)       // bits 14-17
        __syncthreads();   // WAR on sC
        #pragma unroll
        for (int r = 0; r < R; ++r)
            sC[lane | (((unsigned)r | (w << 4)) << 6)] = pk(re[r], im[r]);
        __syncthreads();
        #pragma unroll
        for (int r = 0; r < R; ++r) {
            float2 v = unpk(sC[lane | ((w | ((unsigned)r << 4)) << 6)]);
            re[r] = v.x; im[r] = v.y;
        }
        REGSTAGE(1, cb2, sb2)  REGSTAGE(2, cb2, sb2)
        REGSTAGE(4, cb2, sb2)  REGSTAGE(8, cb2, sb2)       // bits 18-21
        #pragma unroll
        for (int r = 0; r < R; ++r) {
            size_t gi = ((size_t)(w | ((unsigned)r << 4)) << 14) | g0 | lane;
            st[gi] = pk(re[r], im[r]);
        }
    }
    gbar(&bar[32]);

    // ============ P3: layer2 bits 0-13 + fused |c|^2 * hS reduce ============
    {
        const size_t base = (size_t)b << 14;
        #pragma unroll
        for (int r = 0; r < R; ++r) {
            float2 v = unpk(st[base + (lane | (w << 6) | ((unsigned)r << 10))]);
            re[r] = v.x; im[r] = v.y;
        }
        REGSTAGE(1, cb2, sb2)  REGSTAGE(2, cb2, sb2)
        REGSTAGE(4, cb2, sb2)  REGSTAGE(8, cb2, sb2)       // bits 10-13
        SHFLSTAGE(1,  cb2, sb2) SHFLSTAGE(2,  cb2, sb2)
        SHFLSTAGE(4,  cb2, sb2) SHFLSTAGE(8,  cb2, sb2)
        SHFLSTAGE(16, cb2, sb2) SHFLSTAGE(32, cb2, sb2)    // bits 0-5
        __syncthreads();   // WAR on sC from P2
        #pragma unroll
        for (int r = 0; r < R; ++r)
            sC[lane | (w << 6) | ((unsigned)r << 10)] = pk(re[r], im[r]);
        __syncthreads();
        #pragma unroll
        for (int r = 0; r < R; ++r) {
            float2 v = unpk(sC[lane | ((unsigned)r << 6) | (w << 10)]);
            re[r] = v.x; im[r] = v.y;
        }
        REGSTAGE(1, cb2, sb2)  REGSTAGE(2, cb2, sb2)
        REGSTAGE(4, cb2, sb2)  REGSTAGE(8, cb2, sb2)       // bits 6-9
        float acc = 0.f;
        #pragma unroll
        for (int r = 0; r < R; ++r) {
            unsigned i = lane | ((unsigned)r << 6) | (w << 10);
            acc = fmaf(re[r] * re[r] + im[r] * im[r], hS[base + i], acc);
        }
        #pragma unroll
        for (int off = 32; off >= 1; off >>= 1)
            acc += __shfl_down(acc, off, 64);
        float* sF = (float*)sC;
        __syncthreads();   // WAR on sC
        if (lane == 0) sF[w] = acc;
        __syncthreads();
        if (t == 0) {
            float s = 0.f;
            #pragma unroll
            for (int i = 0; i < TPB / 64; ++i) s += sF[i];
            // publish partial (agent-scope, bypasses stale-line issues)
            __hip_atomic_store(&partial[b], s, __ATOMIC_RELAXED, __HIP_MEMORY_SCOPE_AGENT);
            unsigned cnt = __hip_atomic_fetch_add(&bar[64], 1u, __ATOMIC_ACQ_REL,
                                                  __HIP_MEMORY_SCOPE_AGENT);
            if (cnt == NB - 1) {   // last block finishes: sum 256 partials
                float tot = 0.f;
                for (int i = 0; i < NB; ++i)
                    tot += __hip_atomic_load(&partial[i], __ATOMIC_RELAXED,
                                             __HIP_MEMORY_SCOPE_AGENT);
                out[0] = tot;
            }
        }
    }
}

extern "C" void kernel_launch(void* const* d_in, const int* in_sizes, int n_in,
                              void* d_out, int out_size, void* d_ws, size_t ws_size,
                              hipStream_t stream)
{
    (void)in_sizes; (void)n_in; (void)out_size; (void)ws_size;
    const float* h   = (const float*)d_in[0];
    const float* hS  = (const float*)d_in[1];
    const float* gam = (const float*)d_in[2];
    const float* bet = (const float*)d_in[3];
    unsigned* bar     = (unsigned*)d_ws;                    // 3 counters, 128B apart
    float*    partial = (float*)((char*)d_ws + 1024);       // 256 floats
    unsigned* st      = (unsigned*)((char*)d_ws + 8192);    // 16 MB half2 state
    float*    out     = (float*)d_out;

    k_init<<<dim3(1), dim3(64), 0, stream>>>(bar);
    void* args[] = { (void*)&h, (void*)&hS, (void*)&gam, (void*)&bet,
                     (void*)&bar, (void*)&st, (void*)&partial, (void*)&out };
    hipLaunchCooperativeKernel((void*)k_fused, dim3(NB), dim3(TPB),
                               args, 0, stream);
}

// Round 9
// 199.933 us; speedup vs baseline: 2.5406x; 1.6115x over previous
//
#include <hip/hip_runtime.h>

// 22-qubit QAOA state-vector sim — single cooperative-launch kernel, 3 phases,
// hand-rolled grid barrier. R8 lesson: ACQUIRE spin-loads / ACQ_REL arrivals
// emit buffer_inv/buffer_wbl2 PER ITERATION at agent scope -> 256 spinners
// continuously invalidated all 8 per-XCD L2s -> working blocks ran at L3
// latency (478 GB/s effective, VALUBusy 11.7%). R9: cache maintenance ONCE
// per phase (release fence before arrival, acquire fence after spin), spin on
// RELAXED atomic loads (no cache ops).
//   P1: init + phase1 + layer1 bits 0-13  (contiguous 16384-elem tile/block)
//   P2: layer1 bits 14-21 + phase2 + layer2 bits 14-21 (64-col combs, 256B segs)
//   P3: layer2 bits 0-13 + fused |c|^2*hS reduce; LAST block sums partials.

#define NB    256
#define TPB   1024
#define R     16

typedef __fp16 h2_t __attribute__((ext_vector_type(2)));
union PkU { unsigned u; h2_t h; };

__device__ __forceinline__ unsigned pk(float x, float y) {
    PkU p; p.h = __builtin_amdgcn_cvt_pkrtz(x, y); return p.u;
}
__device__ __forceinline__ float2 unpk(unsigned v) {
    PkU p; p.u = v; return make_float2((float)p.h.x, (float)p.h.y);
}

__device__ __forceinline__ void gbar(unsigned* cnt) {
    __syncthreads();                       // drains all waves' stores (vmcnt 0)
    if (threadIdx.x == 0) {
        __builtin_amdgcn_fence(__ATOMIC_RELEASE, "agent");   // buffer_wbl2, once
        __hip_atomic_fetch_add(cnt, 1u, __ATOMIC_RELAXED, __HIP_MEMORY_SCOPE_AGENT);
        while (__hip_atomic_load(cnt, __ATOMIC_RELAXED, __HIP_MEMORY_SCOPE_AGENT) < NB)
            __builtin_amdgcn_s_sleep(8);   // relaxed load: NO cache inv per spin
        __builtin_amdgcn_fence(__ATOMIC_ACQUIRE, "agent");   // buffer_inv, once
    }
    __syncthreads();
}

// register butterfly on register-index bit MASK (f32)
#define REGSTAGE(MASK, CB, SB) {                                  \
    _Pragma("unroll")                                             \
    for (int r0 = 0; r0 < R; ++r0) {                              \
        if ((r0 & (MASK)) == 0) {                                 \
            const int r1 = r0 | (MASK);                           \
            float t0r = re[r0], t0i = im[r0];                     \
            float t1r = re[r1], t1i = im[r1];                     \
            re[r0] = (CB) * t0r - (SB) * t1i;                     \
            im[r0] = (CB) * t0i + (SB) * t1r;                     \
            re[r1] = (CB) * t1r - (SB) * t0i;                     \
            im[r1] = (CB) * t1i + (SB) * t0r;                     \
        } } }

// cross-lane butterfly, one packed-half2 shuffle per element
#define SHFLSTAGE(MASK, CB, SB) {                                 \
    _Pragma("unroll")                                             \
    for (int r = 0; r < R; ++r) {                                 \
        unsigned pv = (unsigned)__shfl_xor((int)pk(re[r], im[r]), (MASK), 64); \
        float2 p = unpk(pv);                                      \
        float tr = re[r], ti = im[r];                             \
        re[r] = (CB) * tr - (SB) * p.y;                           \
        im[r] = (CB) * ti + (SB) * p.x;                           \
    } }

__global__ void k_init(unsigned* bar) {
    if (threadIdx.x < 3) bar[threadIdx.x * 32] = 0u;   // bar0, bar1, done
}

__global__ __launch_bounds__(TPB, 4) void k_fused(
    const float* __restrict__ h, const float* __restrict__ hS,
    const float* __restrict__ gam, const float* __restrict__ bet,
    unsigned* __restrict__ bar, unsigned* __restrict__ st,
    float* __restrict__ partial, float* __restrict__ out)
{
    __shared__ unsigned sC[16384];   // 64 KB packed half2
    const unsigned t = threadIdx.x, lane = t & 63u, w = t >> 6;   // w: 0..15
    const unsigned b = blockIdx.x;
    const float cb1 = __cosf(bet[0]), sb1 = __sinf(bet[0]);
    const float cb2 = __cosf(bet[1]), sb2 = __sinf(bet[1]);
    const float g1 = gam[0], g2 = gam[1];
    float re[R], im[R];

    // ================= P1: init + phase1 + layer1 bits 0-13 =================
    // tile = 16384 contiguous elems at base = b<<14.
    // map A: i = lane | w<<6 | r<<10 ; map B: i = lane | r<<6 | w<<10
    {
        const size_t base = (size_t)b << 14;
        #pragma unroll
        for (int r = 0; r < R; ++r) {
            unsigned i = lane | (w << 6) | ((unsigned)r << 10);
            float s, c;
            __sincosf(g1 * h[base + i], &s, &c);
            re[r] = c * 0x1p-11f;   // 1/sqrt(2^22)
            im[r] = s * 0x1p-11f;
        }
        REGSTAGE(1, cb1, sb1)  REGSTAGE(2, cb1, sb1)
        REGSTAGE(4, cb1, sb1)  REGSTAGE(8, cb1, sb1)       // bits 10-13
        SHFLSTAGE(1,  cb1, sb1) SHFLSTAGE(2,  cb1, sb1)    // bits 0,1
        SHFLSTAGE(4,  cb1, sb1) SHFLSTAGE(8,  cb1, sb1)    // bits 2,3
        SHFLSTAGE(16, cb1, sb1) SHFLSTAGE(32, cb1, sb1)    // bits 4,5
        #pragma unroll
        for (int r = 0; r < R; ++r)
            sC[lane | (w << 6) | ((unsigned)r << 10)] = pk(re[r], im[r]);
        __syncthreads();
        #pragma unroll
        for (int r = 0; r < R; ++r) {
            float2 v = unpk(sC[lane | ((unsigned)r << 6) | (w << 10)]);
            re[r] = v.x; im[r] = v.y;
        }
        REGSTAGE(1, cb1, sb1)  REGSTAGE(2, cb1, sb1)
        REGSTAGE(4, cb1, sb1)  REGSTAGE(8, cb1, sb1)       // bits 6-9
        #pragma unroll
        for (int r = 0; r < R; ++r)
            st[base + (lane | ((unsigned)r << 6) | (w << 10))] = pk(re[r], im[r]);
    }
    gbar(&bar[0]);

    // ======= P2: layer1 bits 14-21 + phase2 + layer2 bits 14-21 =======
    // lo columns g0 = b*64 .. +63 (lane), hi = bits 14-21 (256 values).
    // map A: hi = w | r<<4 ; map B: hi = r | w<<4. Global idx = hi<<14 | g0 | lane.
    {
        const unsigned g0 = b << 6;
        #pragma unroll
        for (int r = 0; r < R; ++r) {
            size_t gi = ((size_t)(w | ((unsigned)r << 4)) << 14) | g0 | lane;
            float2 v = unpk(st[gi]);
            re[r] = v.x; im[r] = v.y;
        }
        REGSTAGE(1, cb1, sb1)  REGSTAGE(2, cb1, sb1)
        REGSTAGE(4, cb1, sb1)  REGSTAGE(8, cb1, sb1)       // bits 18-21
        // T: A -> B  (LDS idx = lane | hi<<6)
        #pragma unroll
        for (int r = 0; r < R; ++r)
            sC[lane | ((w | ((unsigned)r << 4)) << 6)] = pk(re[r], im[r]);
        __syncthreads();
        #pragma unroll
        for (int r = 0; r < R; ++r) {
            float2 v = unpk(sC[lane | (((unsigned)r | (w << 4)) << 6)]);
            re[r] = v.x; im[r] = v.y;
        }
        REGSTAGE(1, cb1, sb1)  REGSTAGE(2, cb1, sb1)
        REGSTAGE(4, cb1, sb1)  REGSTAGE(8, cb1, sb1)       // bits 14-17; L1 done
        // phase2
        #pragma unroll
        for (int r = 0; r < R; ++r) {
            size_t gi = ((size_t)((unsigned)r | (w << 4)) << 14) | g0 | lane;
            float s, c;
            __sincosf(g2 * h[gi], &s, &c);
            float tr = re[r], ti = im[r];
            re[r] = tr * c - ti * s;
            im[r] = tr * s + ti * c;
        }
        // layer2 high
        REGSTAGE(1, cb2, sb2)  REGSTAGE(2, cb2, sb2)
        REGSTAGE(4, cb2, sb2)  REGSTAGE(8, cb2, sb2)       // bits 14-17
        __syncthreads();   // WAR on sC
        #pragma unroll
        for (int r = 0; r < R; ++r)
            sC[lane | (((unsigned)r | (w << 4)) << 6)] = pk(re[r], im[r]);
        __syncthreads();
        #pragma unroll
        for (int r = 0; r < R; ++r) {
            float2 v = unpk(sC[lane | ((w | ((unsigned)r << 4)) << 6)]);
            re[r] = v.x; im[r] = v.y;
        }
        REGSTAGE(1, cb2, sb2)  REGSTAGE(2, cb2, sb2)
        REGSTAGE(4, cb2, sb2)  REGSTAGE(8, cb2, sb2)       // bits 18-21
        #pragma unroll
        for (int r = 0; r < R; ++r) {
            size_t gi = ((size_t)(w | ((unsigned)r << 4)) << 14) | g0 | lane;
            st[gi] = pk(re[r], im[r]);
        }
    }
    gbar(&bar[32]);

    // ============ P3: layer2 bits 0-13 + fused |c|^2 * hS reduce ============
    {
        const size_t base = (size_t)b << 14;
        #pragma unroll
        for (int r = 0; r < R; ++r) {
            float2 v = unpk(st[base + (lane | (w << 6) | ((unsigned)r << 10))]);
            re[r] = v.x; im[r] = v.y;
        }
        REGSTAGE(1, cb2, sb2)  REGSTAGE(2, cb2, sb2)
        REGSTAGE(4, cb2, sb2)  REGSTAGE(8, cb2, sb2)       // bits 10-13
        SHFLSTAGE(1,  cb2, sb2) SHFLSTAGE(2,  cb2, sb2)
        SHFLSTAGE(4,  cb2, sb2) SHFLSTAGE(8,  cb2, sb2)
        SHFLSTAGE(16, cb2, sb2) SHFLSTAGE(32, cb2, sb2)    // bits 0-5
        __syncthreads();   // WAR on sC from P2
        #pragma unroll
        for (int r = 0; r < R; ++r)
            sC[lane | (w << 6) | ((unsigned)r << 10)] = pk(re[r], im[r]);
        __syncthreads();
        #pragma unroll
        for (int r = 0; r < R; ++r) {
            float2 v = unpk(sC[lane | ((unsigned)r << 6) | (w << 10)]);
            re[r] = v.x; im[r] = v.y;
        }
        REGSTAGE(1, cb2, sb2)  REGSTAGE(2, cb2, sb2)
        REGSTAGE(4, cb2, sb2)  REGSTAGE(8, cb2, sb2)       // bits 6-9
        float acc = 0.f;
        #pragma unroll
        for (int r = 0; r < R; ++r) {
            unsigned i = lane | ((unsigned)r << 6) | (w << 10);
            acc = fmaf(re[r] * re[r] + im[r] * im[r], hS[base + i], acc);
        }
        #pragma unroll
        for (int off = 32; off >= 1; off >>= 1)
            acc += __shfl_down(acc, off, 64);
        float* sF = (float*)sC;
        __syncthreads();   // WAR on sC
        if (lane == 0) sF[w] = acc;
        __syncthreads();
        if (t == 0) {
            float s = 0.f;
            #pragma unroll
            for (int i = 0; i < TPB / 64; ++i) s += sF[i];
            // publish partial (agent-scope atomic store -> coherence point)
            __hip_atomic_store(&partial[b], s, __ATOMIC_RELAXED, __HIP_MEMORY_SCOPE_AGENT);
            unsigned cnt = __hip_atomic_fetch_add(&bar[64], 1u, __ATOMIC_ACQ_REL,
                                                  __HIP_MEMORY_SCOPE_AGENT);
            if (cnt == NB - 1) {   // last block finishes: sum 256 partials
                float tot = 0.f;
                for (int i = 0; i < NB; ++i)
                    tot += __hip_atomic_load(&partial[i], __ATOMIC_RELAXED,
                                             __HIP_MEMORY_SCOPE_AGENT);
                out[0] = tot;
            }
        }
    }
}

extern "C" void kernel_launch(void* const* d_in, const int* in_sizes, int n_in,
                              void* d_out, int out_size, void* d_ws, size_t ws_size,
                              hipStream_t stream)
{
    (void)in_sizes; (void)n_in; (void)out_size; (void)ws_size;
    const float* h   = (const float*)d_in[0];
    const float* hS  = (const float*)d_in[1];
    const float* gam = (const float*)d_in[2];
    const float* bet = (const float*)d_in[3];
    unsigned* bar     = (unsigned*)d_ws;                    // 3 counters, 128B apart
    float*    partial = (float*)((char*)d_ws + 1024);       // 256 floats
    unsigned* st      = (unsigned*)((char*)d_ws + 8192);    // 16 MB half2 state
    float*    out     = (float*)d_out;

    k_init<<<dim3(1), dim3(64), 0, stream>>>(bar);
    void* args[] = { (void*)&h, (void*)&hS, (void*)&gam, (void*)&bet,
                     (void*)&bar, (void*)&st, (void*)&partial, (void*)&out };
    hipLaunchCooperativeKernel((void*)k_fused, dim3(NB), dim3(TPB),
                               args, 0, stream);
}

// Round 10
// 179.997 us; speedup vs baseline: 2.8220x; 1.1108x over previous
//
#include <hip/hip_runtime.h>

// 22-qubit QAOA state-vector sim — single kernel, 3 phases, hand-rolled grid
// barrier, PLAIN launch (R9: coop launch costs ~75-90 us vs regular under
// graph replay; co-residency is guaranteed by capacity: 64KB LDS/block ->
// >=2 blocks/CU capacity, so 256 blocks on 256 CUs can never strand).
// R10 also adds DRAM-channel XOR swizzle on the scratch state:
//   phys(x) = x ^ (((x>>14)&63)<<6)
// R9 evidence: P2 reads hi<<14 | b<<6 | lane = 64KB stride, fixed addr[13:6]
// per block -> all of a block's loads camp on one channel group (1.1 TB/s
// effective, VALUBusy 25%). XOR relabeling commutes with butterfly pairings
// (pairs are XOR masks), so P1/P3 st formulas are UNCHANGED; only h/hS reads
// XOR K1=(b&63)<<6 and P2 st addresses use g0^((hi&63)<<6). Lanes untouched.
//   P1: init + phase1 + layer1 bits 0-13  (contiguous 16384-elem tile/block)
//   P2: layer1 bits 14-21 + phase2 + layer2 bits 14-21 (64-col combs)
//   P3: layer2 bits 0-13 + fused |c|^2*hS reduce; LAST block sums partials.
// Barrier: release fence once -> relaxed fetch_add -> relaxed spin (no cache
// ops per iteration — R8 lesson) -> acquire fence once.

#define NB    256
#define TPB   1024
#define R     16

typedef __fp16 h2_t __attribute__((ext_vector_type(2)));
union PkU { unsigned u; h2_t h; };

__device__ __forceinline__ unsigned pk(float x, float y) {
    PkU p; p.h = __builtin_amdgcn_cvt_pkrtz(x, y); return p.u;
}
__device__ __forceinline__ float2 unpk(unsigned v) {
    PkU p; p.u = v; return make_float2((float)p.h.x, (float)p.h.y);
}

__device__ __forceinline__ void gbar(unsigned* cnt) {
    __syncthreads();                       // drains all waves' stores (vmcnt 0)
    if (threadIdx.x == 0) {
        __builtin_amdgcn_fence(__ATOMIC_RELEASE, "agent");   // buffer_wbl2, once
        __hip_atomic_fetch_add(cnt, 1u, __ATOMIC_RELAXED, __HIP_MEMORY_SCOPE_AGENT);
        while (__hip_atomic_load(cnt, __ATOMIC_RELAXED, __HIP_MEMORY_SCOPE_AGENT) < NB)
            __builtin_amdgcn_s_sleep(1);   // relaxed: no cache inv per spin
        __builtin_amdgcn_fence(__ATOMIC_ACQUIRE, "agent");   // buffer_inv, once
    }
    __syncthreads();
}

// register butterfly on register-index bit MASK (f32)
#define REGSTAGE(MASK, CB, SB) {                                  \
    _Pragma("unroll")                                             \
    for (int r0 = 0; r0 < R; ++r0) {                              \
        if ((r0 & (MASK)) == 0) {                                 \
            const int r1 = r0 | (MASK);                           \
            float t0r = re[r0], t0i = im[r0];                     \
            float t1r = re[r1], t1i = im[r1];                     \
            re[r0] = (CB) * t0r - (SB) * t1i;                     \
            im[r0] = (CB) * t0i + (SB) * t1r;                     \
            re[r1] = (CB) * t1r - (SB) * t0i;                     \
            im[r1] = (CB) * t1i + (SB) * t0r;                     \
        } } }

// cross-lane butterfly, one packed-half2 shuffle per element
#define SHFLSTAGE(MASK, CB, SB) {                                 \
    _Pragma("unroll")                                             \
    for (int r = 0; r < R; ++r) {                                 \
        unsigned pv = (unsigned)__shfl_xor((int)pk(re[r], im[r]), (MASK), 64); \
        float2 p = unpk(pv);                                      \
        float tr = re[r], ti = im[r];                             \
        re[r] = (CB) * tr - (SB) * p.y;                           \
        im[r] = (CB) * ti + (SB) * p.x;                           \
    } }

__global__ void k_init(unsigned* bar) {
    if (threadIdx.x < 3) bar[threadIdx.x * 32] = 0u;   // bar0, bar1, done
}

__global__ __launch_bounds__(TPB, 4) void k_fused(
    const float* __restrict__ h, const float* __restrict__ hS,
    const float* __restrict__ gam, const float* __restrict__ bet,
    unsigned* __restrict__ bar, unsigned* __restrict__ st,
    float* __restrict__ partial, float* __restrict__ out)
{
    __shared__ unsigned sC[16384];   // 64 KB packed half2
    const unsigned t = threadIdx.x, lane = t & 63u, w = t >> 6;   // w: 0..15
    const unsigned b = blockIdx.x;
    const unsigned K1 = (b & 63u) << 6;   // channel-swizzle key for this tile
    const float cb1 = __cosf(bet[0]), sb1 = __sinf(bet[0]);
    const float cb2 = __cosf(bet[1]), sb2 = __sinf(bet[1]);
    const float g1 = gam[0], g2 = gam[1];
    float re[R], im[R];

    // ================= P1: init + phase1 + layer1 bits 0-13 =================
    // tile = 16384 contiguous elems at base = b<<14.
    // slot map A: i = lane | w<<6 | r<<10 ; slot map B: i = lane | r<<6 | w<<10
    // slot (r,w) holds NATURAL element (slot_formula ^ K1); st addressing uses
    // the slot formula directly (= swizzled physical layout).
    {
        const size_t base = (size_t)b << 14;
        #pragma unroll
        for (int r = 0; r < R; ++r) {
            unsigned i = (lane | (w << 6) | ((unsigned)r << 10)) ^ K1;  // natural
            float s, c;
            __sincosf(g1 * h[base + i], &s, &c);
            re[r] = c * 0x1p-11f;   // 1/sqrt(2^22)
            im[r] = s * 0x1p-11f;
        }
        REGSTAGE(1, cb1, sb1)  REGSTAGE(2, cb1, sb1)
        REGSTAGE(4, cb1, sb1)  REGSTAGE(8, cb1, sb1)       // bits 10-13
        SHFLSTAGE(1,  cb1, sb1) SHFLSTAGE(2,  cb1, sb1)    // bits 0,1
        SHFLSTAGE(4,  cb1, sb1) SHFLSTAGE(8,  cb1, sb1)    // bits 2,3
        SHFLSTAGE(16, cb1, sb1) SHFLSTAGE(32, cb1, sb1)    // bits 4,5
        #pragma unroll
        for (int r = 0; r < R; ++r)
            sC[lane | (w << 6) | ((unsigned)r << 10)] = pk(re[r], im[r]);
        __syncthreads();
        #pragma unroll
        for (int r = 0; r < R; ++r) {
            float2 v = unpk(sC[lane | ((unsigned)r << 6) | (w << 10)]);
            re[r] = v.x; im[r] = v.y;
        }
        REGSTAGE(1, cb1, sb1)  REGSTAGE(2, cb1, sb1)
        REGSTAGE(4, cb1, sb1)  REGSTAGE(8, cb1, sb1)       // bits 6-9
        #pragma unroll
        for (int r = 0; r < R; ++r)   // slot formula = swizzled phys addr
            st[base + (lane | ((unsigned)r << 6) | (w << 10))] = pk(re[r], im[r]);
    }
    gbar(&bar[0]);

    // ======= P2: layer1 bits 14-21 + phase2 + layer2 bits 14-21 =======
    // lo columns g0 = b*64 .. +63 (lane), hi = bits 14-21 (256 values).
    // map A: hi = w | r<<4 ; map B: hi = r | w<<4.
    // st phys = hi<<14 | (g0 ^ ((hi&63)<<6)) | lane  (channel decorrelation)
    {
        const unsigned g0 = b << 6;
        #pragma unroll
        for (int r = 0; r < R; ++r) {
            unsigned hi = w | ((unsigned)r << 4);
            size_t gi = ((size_t)hi << 14) | (g0 ^ ((hi & 63u) << 6)) | lane;
            float2 v = unpk(st[gi]);
            re[r] = v.x; im[r] = v.y;
        }
        REGSTAGE(1, cb1, sb1)  REGSTAGE(2, cb1, sb1)
        REGSTAGE(4, cb1, sb1)  REGSTAGE(8, cb1, sb1)       // bits 18-21
        // T: A -> B  (LDS idx = lane | hi<<6)
        #pragma unroll
        for (int r = 0; r < R; ++r)
            sC[lane | ((w | ((unsigned)r << 4)) << 6)] = pk(re[r], im[r]);
        __syncthreads();
        #pragma unroll
        for (int r = 0; r < R; ++r) {
            float2 v = unpk(sC[lane | (((unsigned)r | (w << 4)) << 6)]);
            re[r] = v.x; im[r] = v.y;
        }
        REGSTAGE(1, cb1, sb1)  REGSTAGE(2, cb1, sb1)
        REGSTAGE(4, cb1, sb1)  REGSTAGE(8, cb1, sb1)       // bits 14-17; L1 done
        // phase2 (h in NATURAL layout — no swizzle)
        #pragma unroll
        for (int r = 0; r < R; ++r) {
            unsigned hi = (unsigned)r | (w << 4);
            size_t gi = ((size_t)hi << 14) | g0 | lane;
            float s, c;
            __sincosf(g2 * h[gi], &s, &c);
            float tr = re[r], ti = im[r];
            re[r] = tr * c - ti * s;
            im[r] = tr * s + ti * c;
        }
        // layer2 high
        REGSTAGE(1, cb2, sb2)  REGSTAGE(2, cb2, sb2)
        REGSTAGE(4, cb2, sb2)  REGSTAGE(8, cb2, sb2)       // bits 14-17
        __syncthreads();   // WAR on sC
        #pragma unroll
        for (int r = 0; r < R; ++r)
            sC[lane | (((unsigned)r | (w << 4)) << 6)] = pk(re[r], im[r]);
        __syncthreads();
        #pragma unroll
        for (int r = 0; r < R; ++r) {
            float2 v = unpk(sC[lane | ((w | ((unsigned)r << 4)) << 6)]);
            re[r] = v.x; im[r] = v.y;
        }
        REGSTAGE(1, cb2, sb2)  REGSTAGE(2, cb2, sb2)
        REGSTAGE(4, cb2, sb2)  REGSTAGE(8, cb2, sb2)       // bits 18-21
        #pragma unroll
        for (int r = 0; r < R; ++r) {
            unsigned hi = w | ((unsigned)r << 4);
            size_t gi = ((size_t)hi << 14) | (g0 ^ ((hi & 63u) << 6)) | lane;
            st[gi] = pk(re[r], im[r]);
        }
    }
    gbar(&bar[32]);

    // ============ P3: layer2 bits 0-13 + fused |c|^2 * hS reduce ============
    {
        const size_t base = (size_t)b << 14;
        #pragma unroll
        for (int r = 0; r < R; ++r) {   // slot formula = swizzled phys addr
            float2 v = unpk(st[base + (lane | (w << 6) | ((unsigned)r << 10))]);
            re[r] = v.x; im[r] = v.y;
        }
        REGSTAGE(1, cb2, sb2)  REGSTAGE(2, cb2, sb2)
        REGSTAGE(4, cb2, sb2)  REGSTAGE(8, cb2, sb2)       // bits 10-13
        SHFLSTAGE(1,  cb2, sb2) SHFLSTAGE(2,  cb2, sb2)
        SHFLSTAGE(4,  cb2, sb2) SHFLSTAGE(8,  cb2, sb2)
        SHFLSTAGE(16, cb2, sb2) SHFLSTAGE(32, cb2, sb2)    // bits 0-5
        __syncthreads();   // WAR on sC from P2
        #pragma unroll
        for (int r = 0; r < R; ++r)
            sC[lane | (w << 6) | ((unsigned)r << 10)] = pk(re[r], im[r]);
        __syncthreads();
        #pragma unroll
        for (int r = 0; r < R; ++r) {
            float2 v = unpk(sC[lane | ((unsigned)r << 6) | (w << 10)]);
            re[r] = v.x; im[r] = v.y;
        }
        REGSTAGE(1, cb2, sb2)  REGSTAGE(2, cb2, sb2)
        REGSTAGE(4, cb2, sb2)  REGSTAGE(8, cb2, sb2)       // bits 6-9
        float acc = 0.f;
        #pragma unroll
        for (int r = 0; r < R; ++r) {
            unsigned i = (lane | ((unsigned)r << 6) | (w << 10)) ^ K1;  // natural
            acc = fmaf(re[r] * re[r] + im[r] * im[r], hS[base + i], acc);
        }
        #pragma unroll
        for (int off = 32; off >= 1; off >>= 1)
            acc += __shfl_down(acc, off, 64);
        float* sF = (float*)sC;
        __syncthreads();   // WAR on sC
        if (lane == 0) sF[w] = acc;
        __syncthreads();
        if (t == 0) {
            float s = 0.f;
            #pragma unroll
            for (int i = 0; i < TPB / 64; ++i) s += sF[i];
            __hip_atomic_store(&partial[b], s, __ATOMIC_RELAXED, __HIP_MEMORY_SCOPE_AGENT);
            unsigned cnt = __hip_atomic_fetch_add(&bar[64], 1u, __ATOMIC_ACQ_REL,
                                                  __HIP_MEMORY_SCOPE_AGENT);
            if (cnt == NB - 1) {   // last block finishes: sum 256 partials
                float tot = 0.f;
                for (int i = 0; i < NB; ++i)
                    tot += __hip_atomic_load(&partial[i], __ATOMIC_RELAXED,
                                             __HIP_MEMORY_SCOPE_AGENT);
                out[0] = tot;
            }
        }
    }
}

extern "C" void kernel_launch(void* const* d_in, const int* in_sizes, int n_in,
                              void* d_out, int out_size, void* d_ws, size_t ws_size,
                              hipStream_t stream)
{
    (void)in_sizes; (void)n_in; (void)out_size; (void)ws_size;
    const float* h   = (const float*)d_in[0];
    const float* hS  = (const float*)d_in[1];
    const float* gam = (const float*)d_in[2];
    const float* bet = (const float*)d_in[3];
    unsigned* bar     = (unsigned*)d_ws;                    // 3 counters, 128B apart
    float*    partial = (float*)((char*)d_ws + 1024);       // 256 floats
    unsigned* st      = (unsigned*)((char*)d_ws + 8192);    // 16 MB half2 state
    float*    out     = (float*)d_out;

    k_init<<<dim3(1), dim3(64), 0, stream>>>(bar);
    // Plain launch: 256 blocks x 64KB LDS -> capacity >= 2 blocks/CU, whole
    // grid always co-resident; barrier cannot deadlock.
    k_fused<<<dim3(NB), dim3(TPB), 0, stream>>>(h, hS, gam, bet,
                                                bar, st, partial, out);
}